// Round 9
// baseline (85.616 us; speedup 1.0000x reference)
//
#include <hip/hip_runtime.h>
#include <math.h>

#define C 256
#define H 40
#define W 40
#define NROI 64
#define PH 7
#define PW 7
#define HW (H * W)
#define NBIN (PH * PW)

// ---------------- Kernel 1: transpose (blk 0-199) + saliency (blk 200-224) --
// r9 SINGLE-VARIABLE change vs the 72.1-us r8 baseline: saliency unroll
// 16 -> 32 (4 serial load rounds -> 2). Ladder of this lever: unroll 8 -> 16
// was -0.93 us (r8). FP add order unchanged (same sequential i within
// q-group) -> absmax bit-identical. Only 25 blocks affected; +~32 VGPRs is
// occupancy-irrelevant (<1 block/CU).
// Transpose blocks verbatim r7: tile 32x64, grid 200, float4 both
// directions, 2-way/3-way LDS banks (free-to-mild, m136).
// Poison/idempotency: sal fully overwritten each launch; smax via signed
// atomicMax over positive floats beats the negative 0xAAAAAAAA poison.
// LESSONS: (r2) do NOT hand-pipeline the pool row loop — +10.6 us real.
// (prior session) do NOT fuse prep+pool with a flag handshake — +112 us.
__global__ __launch_bounds__(256) void prep_kernel(
    const float* __restrict__ fm, float* __restrict__ fmT,
    float* __restrict__ sal, int* __restrict__ smax_bits) {
  __shared__ float tile[32][65];  // 2-way/3-way banks: free-to-mild (m136)
  __shared__ float part[4][64];
  int blk = blockIdx.x;
  int tid = threadIdx.x;

  if (blk < 200) {  // block-uniform branch: __syncthreads inside is safe
    int pt = blk >> 2;
    int cy = blk & 3;
    int p0 = pt * 32, c0 = cy * 64;
    const float4* fm4 = (const float4*)fm;
    float4* fmT4 = (float4*)fmT;
    // phase A: fm float4 (4 consecutive pixels) -> tile. 2 rounds.
    // per wave: 8 channel-rows x 128B contiguous.
#pragma unroll
    for (int i = 0; i < 2; ++i) {
      int idx = i * 256 + tid;
      int f = idx & 7;    // which float4 within the 32-pixel span
      int cl = idx >> 3;  // channel 0..63
      float4 v = fm4[(c0 + cl) * (HW / 4) + (pt << 3) + f];
      tile[4 * f + 0][cl] = v.x;
      tile[4 * f + 1][cl] = v.y;
      tile[4 * f + 2][cl] = v.z;
      tile[4 * f + 3][cl] = v.w;
    }
    __syncthreads();
    // phase B: tile -> fmT float4 (4 consecutive channels). 2 rounds.
    // per wave: 4 pixel-rows x 256B contiguous.
#pragma unroll
    for (int i = 0; i < 2; ++i) {
      int idx = i * 256 + tid;
      int cf = idx & 15;  // which float4 within the 64-channel span
      int pl = idx >> 4;  // pixel 0..31
      float4 u;
      u.x = tile[pl][4 * cf + 0];
      u.y = tile[pl][4 * cf + 1];
      u.z = tile[pl][4 * cf + 2];
      u.w = tile[pl][4 * cf + 3];
      fmT4[(p0 + pl) * (C / 4) + (cy << 4) + cf] = u;
    }
  } else {
    int p0 = (blk - 200) * 64;
    int pl = tid & 63, q = tid >> 6;
    float acc = 0.0f;
#pragma unroll 32
    for (int i = 0; i < 64; ++i) acc += fm[(q * 64 + i) * HW + p0 + pl];
    part[q][pl] = acc;
    __syncthreads();
    if (tid < 64) {
      float s = part[0][tid] + part[1][tid] + part[2][tid] + part[3][tid];
      sal[p0 + tid] = s;
      float m = s;
#pragma unroll
      for (int off = 32; off > 0; off >>= 1) m = fmaxf(m, __shfl_down(m, off));
      if (tid == 0) atomicMax(smax_bits, __float_as_int(m));
    }
  }
}

// ---------------- Kernel 2: pool. wave = (roi, bin); lane = 4 channels -------
// VERBATIM r6/r7/r8 (72.1 us baseline). grid 64 x 13 blocks; block 256 thr =
// 4 waves = 4 bins. Compute loop compiler-pipelined (7-wide independent row
// loads; clamped duplicate columns are max-idempotent L1 hits; per-column
// inside-x tests hoisted). Store phase staged through stage[256][5] so lanes
// write consecutive dwords (coalescer merges 4-per-64B-line); out rows are
// 196B so real float4 stores would be misaligned — dword stores by design.
__global__ __launch_bounds__(256) void pool_kernel(
    const float4* __restrict__ fmT4, const float* __restrict__ rois1,
    const float* __restrict__ rois2, const float* __restrict__ sal,
    const int* __restrict__ smax_bits, float* __restrict__ out) {
  __shared__ float stage[256][5];  // [channel][bin-local], pad 5
  int blk = blockIdx.x;
  int n = blk / 13;
  int g = blk - n * 13;
  int w = threadIdx.x >> 6;
  int l = threadIdx.x & 63;
  int b = g * 4 + w;

  if (b < NBIN) {  // wave-uniform predicate (replaces early return)
    const float* r1 = rois1 + n * 5;
    const float* r2 = rois2 + n * 5;
    // jnp.round = round-half-to-even = rintf under default rounding mode.
    int x1a = min((int)rintf(r1[1] * 0.0625f), W - 1);
    int y1a = min((int)rintf(r1[2] * 0.0625f), H - 1);
    int x2a = min((int)rintf(r1[3] * 0.0625f), W - 1);
    int y2a = min((int)rintf(r1[4] * 0.0625f), H - 1);
    int x1b = min((int)rintf(r2[1] * 0.0625f), W - 1);
    int y1b = min((int)rintf(r2[2] * 0.0625f), H - 1);
    int x2b = min((int)rintf(r2[3] * 0.0625f), W - 1);
    int y2b = min((int)rintf(r2[4] * 0.0625f), H - 1);

    int ux1 = min(x1a, x1b), uy1 = min(y1a, y1b);
    int ux2 = max(x2a, x2b), uy2 = max(y2a, y2b);
    int hb = uy2 - uy1 + 1, wb = ux2 - ux1 + 1;

    int ph = b / PW, pw = b - (b / PW) * PW;
    int ys0 = uy1 + (ph * hb) / PH;
    int ys1 = uy1 + ((ph + 1) * hb + PH - 1) / PH;
    int xs0 = ux1 + (pw * wb) / PW;
    int xs1 = ux1 + ((pw + 1) * wb + PW - 1) / PW;
    // bin is never empty: ys1 > ys0, xs1 > xs0. Bin width <= 7.

    float inv = 1.0f / __int_as_float(*smax_bits);

    int xl = xs1 - 1;  // last valid column; clamped dups are max-idempotent
    int xc0 = xs0;
    int xc1 = min(xs0 + 1, xl);
    int xc2 = min(xs0 + 2, xl);
    int xc3 = min(xs0 + 3, xl);
    int xc4 = min(xs0 + 4, xl);
    int xc5 = min(xs0 + 5, xl);
    int xc6 = min(xs0 + 6, xl);
    // per-column float4-element offsets (row base added per row)
    int a0 = xc0 * 64 + l, a1 = xc1 * 64 + l, a2 = xc2 * 64 + l;
    int a3 = xc3 * 64 + l, a4 = xc4 * 64 + l, a5 = xc5 * 64 + l;
    int a6 = xc6 * 64 + l;
    // per-column inside-x tests, hoisted out of the row loop
    bool cxa0 = (xc0 >= x1a) & (xc0 <= x2a), cxb0 = (xc0 >= x1b) & (xc0 <= x2b);
    bool cxa1 = (xc1 >= x1a) & (xc1 <= x2a), cxb1 = (xc1 >= x1b) & (xc1 <= x2b);
    bool cxa2 = (xc2 >= x1a) & (xc2 <= x2a), cxb2 = (xc2 >= x1b) & (xc2 <= x2b);
    bool cxa3 = (xc3 >= x1a) & (xc3 <= x2a), cxb3 = (xc3 >= x1b) & (xc3 <= x2b);
    bool cxa4 = (xc4 >= x1a) & (xc4 <= x2a), cxb4 = (xc4 >= x1b) & (xc4 <= x2b);
    bool cxa5 = (xc5 >= x1a) & (xc5 <= x2a), cxb5 = (xc5 >= x1b) & (xc5 <= x2b);
    bool cxa6 = (xc6 >= x1a) & (xc6 <= x2a), cxb6 = (xc6 >= x1b) & (xc6 <= x2b);

    float4 best = make_float4(-INFINITY, -INFINITY, -INFINITY, -INFINITY);

    for (int y = ys0; y < ys1; ++y) {
      bool iya = (y >= y1a) & (y <= y2a);
      bool iyb = (y >= y1b) & (y <= y2b);
      int rb = y * W;
      int rb64 = rb * 64;
      // 7 independent vector loads + 7 uniform sal loads: deep MLP, no
      // serial address chain. Duplicated columns re-hit the same L1 line.
      float4 v0 = fmT4[rb64 + a0];
      float4 v1 = fmT4[rb64 + a1];
      float4 v2 = fmT4[rb64 + a2];
      float4 v3 = fmT4[rb64 + a3];
      float4 v4 = fmT4[rb64 + a4];
      float4 v5 = fmT4[rb64 + a5];
      float4 v6 = fmT4[rb64 + a6];
      float s0 = sal[rb + xc0];
      float s1 = sal[rb + xc1];
      float s2 = sal[rb + xc2];
      float s3 = sal[rb + xc3];
      float s4 = sal[rb + xc4];
      float s5 = sal[rb + xc5];
      float s6 = sal[rb + xc6];

#define UPD(K)                                                         \
  {                                                                    \
    bool ins = (iya & cxa##K) | (iyb & cxb##K);                        \
    float qq = s##K * inv;                                             \
    qq = qq * qq;                                                      \
    qq = qq * qq;                                                      \
    float m = ins ? 1.0f : fmaf(0.4f, qq, 0.5f);                       \
    best.x = fmaxf(best.x, v##K.x * m);                                \
    best.y = fmaxf(best.y, v##K.y * m);                                \
    best.z = fmaxf(best.z, v##K.z * m);                                \
    best.w = fmaxf(best.w, v##K.w * m);                                \
  }
      UPD(0)
      UPD(1)
      UPD(2)
      UPD(3)
      UPD(4)
      UPD(5)
      UPD(6)
#undef UPD
    }

    // stage results: channel 4l+k, bin-local w
    stage[4 * l + 0][w] = best.x;
    stage[4 * l + 1][w] = best.y;
    stage[4 * l + 2][w] = best.z;
    stage[4 * l + 3][w] = best.w;
  }
  __syncthreads();

  // store phase: enumerate (c, wl) in out-address order so consecutive lanes
  // hit consecutive dwords (4 per 64B line -> wave coalescer merges).
  int tid = threadIdx.x;
#pragma unroll
  for (int j = 0; j < 4; ++j) {
    int idx = j * 256 + tid;
    int c = idx >> 2;
    int wl = idx & 3;
    int bb = 4 * g + wl;
    if (bb < NBIN) out[(n * C + c) * NBIN + bb] = stage[c][wl];
  }
}

extern "C" void kernel_launch(void* const* d_in, const int* in_sizes, int n_in,
                              void* d_out, int out_size, void* d_ws,
                              size_t ws_size, hipStream_t stream) {
  const float* fm = (const float*)d_in[0];
  const float* r1 = (const float*)d_in[1];
  const float* r2 = (const float*)d_in[2];
  float* out = (float*)d_out;

  char* ws = (char*)d_ws;
  float* sal = (float*)ws;                           // 1600 floats @ 0
  int* smax_bits = (int*)(ws + HW * sizeof(float));  // 1 int @ 6400
  float* fmT = (float*)(ws + 16384);                 // HW*C floats, 16B aligned

  prep_kernel<<<225, 256, 0, stream>>>(fm, fmT, sal, smax_bits);
  pool_kernel<<<NROI * 13, 256, 0, stream>>>((const float4*)fmT, r1, r2, sal,
                                             smax_bits, out);
}

// Round 10
// 71.218 us; speedup vs baseline: 1.2022x; 1.2022x over previous
//
#include <hip/hip_runtime.h>
#include <math.h>

#define C 256
#define H 40
#define W 40
#define NROI 64
#define PH 7
#define PW 7
#define HW (H * W)
#define NBIN (PH * PW)

// ---------------- Kernel 1: transpose (blk 0-199) + saliency (blk 200-224) --
// r10 = VERBATIM REVERT to r8 (72.06 us, session best).
// r9 LESSON (measured twice): saliency unroll >= 32 is a CLIFF —
// unroll 8->16 = -0.9 us (r8), 16->32 = +13.5 us (r9). r2's +10.6 us bundle
// regression is hereby re-attributed primarily to its unroll-64 saliency
// (float4 transpose was cleared at -0.45 in r5). DO NOT deepen this unroll
// past 16; do not hand-pipeline around it either.
// Transpose blocks: tile 32x64, grid 200, float4 both directions,
// 2-way/3-way LDS banks (free-to-mild, m136).
// Poison/idempotency: sal fully overwritten each launch; smax via signed
// atomicMax over positive floats beats the negative 0xAAAAAAAA poison.
// LESSONS: (r2/r9) saliency deep-unroll cliff. (r2) do NOT hand-pipeline the
// pool row loop. (prior session) do NOT fuse prep+pool with a flag
// handshake — +112 us spin-wait vs ~6 us node boundary.
__global__ __launch_bounds__(256) void prep_kernel(
    const float* __restrict__ fm, float* __restrict__ fmT,
    float* __restrict__ sal, int* __restrict__ smax_bits) {
  __shared__ float tile[32][65];  // 2-way/3-way banks: free-to-mild (m136)
  __shared__ float part[4][64];
  int blk = blockIdx.x;
  int tid = threadIdx.x;

  if (blk < 200) {  // block-uniform branch: __syncthreads inside is safe
    int pt = blk >> 2;
    int cy = blk & 3;
    int p0 = pt * 32, c0 = cy * 64;
    const float4* fm4 = (const float4*)fm;
    float4* fmT4 = (float4*)fmT;
    // phase A: fm float4 (4 consecutive pixels) -> tile. 2 rounds.
    // per wave: 8 channel-rows x 128B contiguous.
#pragma unroll
    for (int i = 0; i < 2; ++i) {
      int idx = i * 256 + tid;
      int f = idx & 7;    // which float4 within the 32-pixel span
      int cl = idx >> 3;  // channel 0..63
      float4 v = fm4[(c0 + cl) * (HW / 4) + (pt << 3) + f];
      tile[4 * f + 0][cl] = v.x;
      tile[4 * f + 1][cl] = v.y;
      tile[4 * f + 2][cl] = v.z;
      tile[4 * f + 3][cl] = v.w;
    }
    __syncthreads();
    // phase B: tile -> fmT float4 (4 consecutive channels). 2 rounds.
    // per wave: 4 pixel-rows x 256B contiguous.
#pragma unroll
    for (int i = 0; i < 2; ++i) {
      int idx = i * 256 + tid;
      int cf = idx & 15;  // which float4 within the 64-channel span
      int pl = idx >> 4;  // pixel 0..31
      float4 u;
      u.x = tile[pl][4 * cf + 0];
      u.y = tile[pl][4 * cf + 1];
      u.z = tile[pl][4 * cf + 2];
      u.w = tile[pl][4 * cf + 3];
      fmT4[(p0 + pl) * (C / 4) + (cy << 4) + cf] = u;
    }
  } else {
    int p0 = (blk - 200) * 64;
    int pl = tid & 63, q = tid >> 6;
    float acc = 0.0f;
#pragma unroll 16
    for (int i = 0; i < 64; ++i) acc += fm[(q * 64 + i) * HW + p0 + pl];
    part[q][pl] = acc;
    __syncthreads();
    if (tid < 64) {
      float s = part[0][tid] + part[1][tid] + part[2][tid] + part[3][tid];
      sal[p0 + tid] = s;
      float m = s;
#pragma unroll
      for (int off = 32; off > 0; off >>= 1) m = fmaxf(m, __shfl_down(m, off));
      if (tid == 0) atomicMax(smax_bits, __float_as_int(m));
    }
  }
}

// ---------------- Kernel 2: pool. wave = (roi, bin); lane = 4 channels -------
// VERBATIM r6/r7/r8 (72.06 us baseline). grid 64 x 13 blocks; block 256 thr =
// 4 waves = 4 bins. Compute loop compiler-pipelined (7-wide independent row
// loads; clamped duplicate columns are max-idempotent L1 hits; per-column
// inside-x tests hoisted). Store phase staged through stage[256][5] so lanes
// write consecutive dwords (coalescer merges 4-per-64B-line); out rows are
// 196B so real float4 stores would be misaligned — dword stores by design.
__global__ __launch_bounds__(256) void pool_kernel(
    const float4* __restrict__ fmT4, const float* __restrict__ rois1,
    const float* __restrict__ rois2, const float* __restrict__ sal,
    const int* __restrict__ smax_bits, float* __restrict__ out) {
  __shared__ float stage[256][5];  // [channel][bin-local], pad 5
  int blk = blockIdx.x;
  int n = blk / 13;
  int g = blk - n * 13;
  int w = threadIdx.x >> 6;
  int l = threadIdx.x & 63;
  int b = g * 4 + w;

  if (b < NBIN) {  // wave-uniform predicate (replaces early return)
    const float* r1 = rois1 + n * 5;
    const float* r2 = rois2 + n * 5;
    // jnp.round = round-half-to-even = rintf under default rounding mode.
    int x1a = min((int)rintf(r1[1] * 0.0625f), W - 1);
    int y1a = min((int)rintf(r1[2] * 0.0625f), H - 1);
    int x2a = min((int)rintf(r1[3] * 0.0625f), W - 1);
    int y2a = min((int)rintf(r1[4] * 0.0625f), H - 1);
    int x1b = min((int)rintf(r2[1] * 0.0625f), W - 1);
    int y1b = min((int)rintf(r2[2] * 0.0625f), H - 1);
    int x2b = min((int)rintf(r2[3] * 0.0625f), W - 1);
    int y2b = min((int)rintf(r2[4] * 0.0625f), H - 1);

    int ux1 = min(x1a, x1b), uy1 = min(y1a, y1b);
    int ux2 = max(x2a, x2b), uy2 = max(y2a, y2b);
    int hb = uy2 - uy1 + 1, wb = ux2 - ux1 + 1;

    int ph = b / PW, pw = b - (b / PW) * PW;
    int ys0 = uy1 + (ph * hb) / PH;
    int ys1 = uy1 + ((ph + 1) * hb + PH - 1) / PH;
    int xs0 = ux1 + (pw * wb) / PW;
    int xs1 = ux1 + ((pw + 1) * wb + PW - 1) / PW;
    // bin is never empty: ys1 > ys0, xs1 > xs0. Bin width <= 7.

    float inv = 1.0f / __int_as_float(*smax_bits);

    int xl = xs1 - 1;  // last valid column; clamped dups are max-idempotent
    int xc0 = xs0;
    int xc1 = min(xs0 + 1, xl);
    int xc2 = min(xs0 + 2, xl);
    int xc3 = min(xs0 + 3, xl);
    int xc4 = min(xs0 + 4, xl);
    int xc5 = min(xs0 + 5, xl);
    int xc6 = min(xs0 + 6, xl);
    // per-column float4-element offsets (row base added per row)
    int a0 = xc0 * 64 + l, a1 = xc1 * 64 + l, a2 = xc2 * 64 + l;
    int a3 = xc3 * 64 + l, a4 = xc4 * 64 + l, a5 = xc5 * 64 + l;
    int a6 = xc6 * 64 + l;
    // per-column inside-x tests, hoisted out of the row loop
    bool cxa0 = (xc0 >= x1a) & (xc0 <= x2a), cxb0 = (xc0 >= x1b) & (xc0 <= x2b);
    bool cxa1 = (xc1 >= x1a) & (xc1 <= x2a), cxb1 = (xc1 >= x1b) & (xc1 <= x2b);
    bool cxa2 = (xc2 >= x1a) & (xc2 <= x2a), cxb2 = (xc2 >= x1b) & (xc2 <= x2b);
    bool cxa3 = (xc3 >= x1a) & (xc3 <= x2a), cxb3 = (xc3 >= x1b) & (xc3 <= x2b);
    bool cxa4 = (xc4 >= x1a) & (xc4 <= x2a), cxb4 = (xc4 >= x1b) & (xc4 <= x2b);
    bool cxa5 = (xc5 >= x1a) & (xc5 <= x2a), cxb5 = (xc5 >= x1b) & (xc5 <= x2b);
    bool cxa6 = (xc6 >= x1a) & (xc6 <= x2a), cxb6 = (xc6 >= x1b) & (xc6 <= x2b);

    float4 best = make_float4(-INFINITY, -INFINITY, -INFINITY, -INFINITY);

    for (int y = ys0; y < ys1; ++y) {
      bool iya = (y >= y1a) & (y <= y2a);
      bool iyb = (y >= y1b) & (y <= y2b);
      int rb = y * W;
      int rb64 = rb * 64;
      // 7 independent vector loads + 7 uniform sal loads: deep MLP, no
      // serial address chain. Duplicated columns re-hit the same L1 line.
      float4 v0 = fmT4[rb64 + a0];
      float4 v1 = fmT4[rb64 + a1];
      float4 v2 = fmT4[rb64 + a2];
      float4 v3 = fmT4[rb64 + a3];
      float4 v4 = fmT4[rb64 + a4];
      float4 v5 = fmT4[rb64 + a5];
      float4 v6 = fmT4[rb64 + a6];
      float s0 = sal[rb + xc0];
      float s1 = sal[rb + xc1];
      float s2 = sal[rb + xc2];
      float s3 = sal[rb + xc3];
      float s4 = sal[rb + xc4];
      float s5 = sal[rb + xc5];
      float s6 = sal[rb + xc6];

#define UPD(K)                                                         \
  {                                                                    \
    bool ins = (iya & cxa##K) | (iyb & cxb##K);                        \
    float qq = s##K * inv;                                             \
    qq = qq * qq;                                                      \
    qq = qq * qq;                                                      \
    float m = ins ? 1.0f : fmaf(0.4f, qq, 0.5f);                       \
    best.x = fmaxf(best.x, v##K.x * m);                                \
    best.y = fmaxf(best.y, v##K.y * m);                                \
    best.z = fmaxf(best.z, v##K.z * m);                                \
    best.w = fmaxf(best.w, v##K.w * m);                                \
  }
      UPD(0)
      UPD(1)
      UPD(2)
      UPD(3)
      UPD(4)
      UPD(5)
      UPD(6)
#undef UPD
    }

    // stage results: channel 4l+k, bin-local w
    stage[4 * l + 0][w] = best.x;
    stage[4 * l + 1][w] = best.y;
    stage[4 * l + 2][w] = best.z;
    stage[4 * l + 3][w] = best.w;
  }
  __syncthreads();

  // store phase: enumerate (c, wl) in out-address order so consecutive lanes
  // hit consecutive dwords (4 per 64B line -> wave coalescer merges).
  int tid = threadIdx.x;
#pragma unroll
  for (int j = 0; j < 4; ++j) {
    int idx = j * 256 + tid;
    int c = idx >> 2;
    int wl = idx & 3;
    int bb = 4 * g + wl;
    if (bb < NBIN) out[(n * C + c) * NBIN + bb] = stage[c][wl];
  }
}

extern "C" void kernel_launch(void* const* d_in, const int* in_sizes, int n_in,
                              void* d_out, int out_size, void* d_ws,
                              size_t ws_size, hipStream_t stream) {
  const float* fm = (const float*)d_in[0];
  const float* r1 = (const float*)d_in[1];
  const float* r2 = (const float*)d_in[2];
  float* out = (float*)d_out;

  char* ws = (char*)d_ws;
  float* sal = (float*)ws;                           // 1600 floats @ 0
  int* smax_bits = (int*)(ws + HW * sizeof(float));  // 1 int @ 6400
  float* fmT = (float*)(ws + 16384);                 // HW*C floats, 16B aligned

  prep_kernel<<<225, 256, 0, stream>>>(fm, fmT, sal, smax_bits);
  pool_kernel<<<NROI * 13, 256, 0, stream>>>((const float4*)fmT, r1, r2, sal,
                                             smax_bits, out);
}